// Round 9
// baseline (213.297 us; speedup 1.0000x reference)
//
#include <hip/hip_runtime.h>

typedef _Float16 half_t;
typedef __attribute__((ext_vector_type(8))) _Float16 half8;
typedef __attribute__((ext_vector_type(4))) float f32x4;

#define BB 64
#define II 512
#define DD 128
#define NN 32
#define OO 64

// load 8 contiguous u-elements (fp16) as fp32
__device__ inline void load8u(const half_t* p, float* a) {
  half8 v = *(const half8*)p;
  #pragma unroll
  for (int e = 0; e < 8; ++e) a[e] = (float)v[e];
}

// ---------------------------------------------------------------------------
// K1: u[b,n,i,o] = sum_d x[b,i,d] * W[n,i,o,d] via fp16 MFMA (validated r8,
// absmax 2.0). This round: A-fragments hoisted to VGPRs (j-invariant) and
// As unioned with Cs (both 16 KB) -> LDS 48->32 KB -> 5 blocks/CU by LDS,
// more TLP to hide the B-stage vmcnt drain.
// Safety of the union: A-frag reads happen before the j=0 loop-top barrier;
// the first Cs write happens after the subsequent post-stage-B barrier.
// ---------------------------------------------------------------------------
__global__ __launch_bounds__(256) void k_compute_u(
    const float* __restrict__ x, const float* __restrict__ W,
    half_t* __restrict__ u)
{
  __shared__ unsigned char AsCs[16384] __attribute__((aligned(16)));
  __shared__ half_t Bs[64*128] __attribute__((aligned(16)));
  half_t* As = (half_t*)AsCs;   // 64 x 128 fp16, XOR-swizzled rows
  float*  Cs = (float*)AsCs;    // 64 x 64 fp32 (after A-frag hoist)
  const int tid  = threadIdx.x;
  const int i    = blockIdx.x;
  const int n0   = blockIdx.y * 8;
  const int w    = tid >> 6;
  const int lane = tid & 63;

  // stage A = x[:, i, :]  (64 b-rows x 128 d), fp32 -> fp16
  for (int k = 0; k < 4; ++k) {
    int flat = tid + 256*k;      // 1024 chunks of 8 floats
    int row  = flat >> 4;
    int c8   = flat & 15;
    const float* gp = x + ((size_t)row*II + i)*DD + c8*8;
    float4 f0 = *(const float4*)(gp);
    float4 f1 = *(const float4*)(gp + 4);
    half8 v;
    v[0]=(half_t)f0.x; v[1]=(half_t)f0.y; v[2]=(half_t)f0.z; v[3]=(half_t)f0.w;
    v[4]=(half_t)f1.x; v[5]=(half_t)f1.y; v[6]=(half_t)f1.z; v[7]=(half_t)f1.w;
    int off = (row*256 + c8*16) ^ ((row & 7) << 4);
    *(half8*)((char*)As + off) = v;
  }
  __syncthreads();

  // hoist A-fragments to registers (j-invariant): lane m=lane&15,
  // k=(lane>>4)*8+e per kk-slice of 32
  half8 av[4];
  {
    int ra = w*16 + (lane & 15);
    #pragma unroll
    for (int kk = 0; kk < 4; ++kk) {
      int aoff = (ra*256 + kk*64 + ((lane >> 4) << 4)) ^ ((ra & 7) << 4);
      av[kk] = *(half8*)((char*)As + aoff);
    }
  }

  for (int j = 0; j < 8; ++j) {
    int n = n0 + j;
    __syncthreads();  // j=0: A-frag reads done; j>0: Cs consumed, Bs free

    // stage B = W[n, i, :, :]  (64 o-rows x 128 d), fp32 -> fp16
    const float* wbase = W + (((size_t)n*II + i)*OO)*DD;
    for (int k = 0; k < 4; ++k) {
      int flat = tid + 256*k;
      int row  = flat >> 4;
      int c8   = flat & 15;
      const float* gp = wbase + row*DD + c8*8;
      float4 f0 = *(const float4*)(gp);
      float4 f1 = *(const float4*)(gp + 4);
      half8 v;
      v[0]=(half_t)f0.x; v[1]=(half_t)f0.y; v[2]=(half_t)f0.z; v[3]=(half_t)f0.w;
      v[4]=(half_t)f1.x; v[5]=(half_t)f1.y; v[6]=(half_t)f1.z; v[7]=(half_t)f1.w;
      int off = (row*256 + c8*16) ^ ((row & 7) << 4);
      *(half8*)((char*)Bs + off) = v;
    }
    __syncthreads();

    f32x4 zero = {0.f, 0.f, 0.f, 0.f};
    f32x4 acc[4];
    #pragma unroll
    for (int ot = 0; ot < 4; ++ot) acc[ot] = zero;

    #pragma unroll
    for (int kk = 0; kk < 4; ++kk) {
      #pragma unroll
      for (int ot = 0; ot < 4; ++ot) {
        int rb   = ot*16 + (lane & 15);
        int boff = (rb*256 + kk*64 + ((lane >> 4) << 4)) ^ ((rb & 7) << 4);
        half8 bv = *(half8*)((char*)Bs + boff);
        acc[ot] = __builtin_amdgcn_mfma_f32_16x16x32_f16(av[kk], bv, acc[ot], 0, 0, 0);
      }
    }

    // D lane map: col = lane&15, row = (lane>>4)*4 + r  (m89-verified)
    #pragma unroll
    for (int ot = 0; ot < 4; ++ot)
      #pragma unroll
      for (int r = 0; r < 4; ++r) {
        int row = w*16 + ((lane >> 4) << 2) + r;
        int col = ot*16 + (lane & 15);
        Cs[row*64 + col] = acc[ot][r];
      }
    __syncthreads();

    // coalesced store Cs -> u[b, n, i, :] as fp16
    for (int k = 0; k < 2; ++k) {
      int flat = tid + 256*k;   // 512 chunks of 8
      int row  = flat >> 3;     // b
      int c8   = flat & 7;
      const float* sp = Cs + row*64 + c8*8;
      half8 v;
      #pragma unroll
      for (int e = 0; e < 8; ++e) v[e] = (half_t)sp[e];
      *(half8*)(u + (((size_t)row*NN + n)*II + i)*OO + c8*8) = v;
    }
  }
}

// ---------------------------------------------------------------------------
// K2: out0[b,n,o] = (1/32) * sum_i u[b,n,i,o]   (validated rounds 3-8)
// ---------------------------------------------------------------------------
__global__ __launch_bounds__(256) void k_round0(
    const half_t* __restrict__ u, float* __restrict__ out0)
{
  __shared__ float sPart[32*65];
  const int tid = threadIdx.x;
  const int bn  = blockIdx.x;          // b*32+n
  const int ip  = tid >> 3;
  const int o8  = tid & 7;
  const half_t* base = u + (size_t)bn * (II*OO);
  float a[8];
  #pragma unroll
  for (int e = 0; e < 8; ++e) a[e] = 0.f;
  for (int i = ip; i < II; i += 32) {
    float t[8];
    load8u(base + (size_t)i*OO + o8*8, t);
    #pragma unroll
    for (int e = 0; e < 8; ++e) a[e] += t[e];
  }
  #pragma unroll
  for (int e = 0; e < 8; ++e) sPart[ip*65 + o8*8 + e] = a[e];
  for (int step = 16; step >= 1; step >>= 1) {
    __syncthreads();
    if (ip < step) {
      #pragma unroll
      for (int e = 0; e < 8; ++e)
        sPart[ip*65 + o8*8 + e] += sPart[(ip+step)*65 + o8*8 + e];
    }
  }
  __syncthreads();
  if (tid < 64) out0[(size_t)bn*OO + tid] = sPart[tid] * (1.f/32.f);
}

// ---------------------------------------------------------------------------
// K3: register-fused routing round — ONE pass over u per round.
// (validated rounds 5-8)
// ---------------------------------------------------------------------------
__global__ __launch_bounds__(256, 2) void k_round_reg(
    const half_t* __restrict__ u, const float* __restrict__ out_prev,
    float* __restrict__ part)
{
  __shared__ float sOut[NN*OO];        // 8 KB
  __shared__ float sP[NN][16][9];      // 18 KB (pad 9 kills 8-way conflicts)
  __shared__ float sLog[16][NN+1];
  __shared__ float sC[16][NN+1];
  const int tid = threadIdx.x;
  const int ic  = blockIdx.x;          // 0..7
  const int b   = blockIdx.y;
  const int n   = tid >> 3;
  const int q   = tid & 7;

  for (int k = 0; k < 8; ++k) {
    int flat = tid + 256*k;
    sOut[flat] = out_prev[(size_t)b*NN*OO + flat];
  }
  float a8[8];
  #pragma unroll
  for (int e = 0; e < 8; ++e) a8[e] = 0.f;
  __syncthreads();

  const half_t* ubase = u + ((size_t)b*NN + n)*II*OO;
  for (int s = 0; s < 4; ++s) {
    const int i0 = ic*64 + s*16;
    float r[16][8];
    // phase 1: load 16 i-rows' o-chunk into regs + partial logit dots
    #pragma unroll
    for (int ii = 0; ii < 16; ++ii) {
      load8u(ubase + (size_t)(i0+ii)*OO + q*8, r[ii]);
      float acc = 0.f;
      #pragma unroll
      for (int e = 0; e < 8; ++e) acc += r[ii][e] * sOut[n*OO + q*8 + e];
      sP[n][ii][q] = acc;
    }
    __syncthreads();
    // logits: thread handles ii = q and q+8
    #pragma unroll
    for (int h = 0; h < 2; ++h) {
      int ii = q + h*8;
      float sum = 0.f;
      #pragma unroll
      for (int q2 = 0; q2 < 8; ++q2) sum += sP[n][ii][q2];
      sLog[ii][n] = sum;
    }
    __syncthreads();
    // softmax over n (redundant, fixed order -> deterministic)
    #pragma unroll
    for (int h = 0; h < 2; ++h) {
      int ii = q + h*8;
      float m = -1e30f;
      #pragma unroll
      for (int n2 = 0; n2 < NN; ++n2) m = fmaxf(m, sLog[ii][n2]);
      float ss = 0.f;
      #pragma unroll
      for (int n2 = 0; n2 < NN; ++n2) ss += __expf(sLog[ii][n2] - m);
      sC[ii][n] = __expf(sLog[ii][n] - m) / ss;
    }
    __syncthreads();
    // phase 2: entirely from registers
    #pragma unroll
    for (int ii = 0; ii < 16; ++ii) {
      float cv = sC[ii][n];
      #pragma unroll
      for (int e = 0; e < 8; ++e) a8[e] += cv * r[ii][e];
    }
  }
  float* dst = part + (((size_t)ic*BB + b)*NN + n)*OO + q*8;
  #pragma unroll
  for (int e = 0; e < 8; ++e) dst[e] = a8[e];
}

// ---------------------------------------------------------------------------
// K3b: out_next[j] = sum_{k<8} part[k][j], fixed order.
// ---------------------------------------------------------------------------
__global__ __launch_bounds__(256) void k_reduce_part(
    const float* __restrict__ part, float* __restrict__ out_next)
{
  const int j = blockIdx.x*256 + threadIdx.x;   // grid = 512
  const size_t O = (size_t)BB*NN*OO;
  float s = 0.f;
  #pragma unroll
  for (int k = 0; k < 8; ++k) s += part[(size_t)k*O + j];
  out_next[j] = s;
}

// ---------------------------------------------------------------------------
// K4: fused final reduce + lengths (validated round 8)
// ---------------------------------------------------------------------------
__global__ __launch_bounds__(64) void k_reduce_len(
    const float* __restrict__ part, float* __restrict__ dout)
{
  const int bn = blockIdx.x;           // 0 .. B*N-1
  const int o  = threadIdx.x;          // 0..63
  const size_t O = (size_t)BB*NN*OO;
  float s = 0.f;
  #pragma unroll
  for (int k = 0; k < 8; ++k) s += part[(size_t)k*O + (size_t)bn*OO + o];
  float sq = s * s;
  #pragma unroll
  for (int d = 32; d >= 1; d >>= 1) sq += __shfl_xor(sq, d, 64);
  if (o == 0) dout[bn] = sqrtf(sq);
}

extern "C" void kernel_launch(void* const* d_in, const int* in_sizes, int n_in,
                              void* d_out, int out_size, void* d_ws, size_t ws_size,
                              hipStream_t stream)
{
  const float* x = (const float*)d_in[0];
  const float* W = (const float*)d_in[1];
  float* dout = (float*)d_out;

  const size_t U = (size_t)BB*NN*II*OO;   // 67,108,864 elements
  const size_t O = (size_t)BB*NN*OO;      // 131,072

  half_t* u   = (half_t*)d_ws;                      // 128 MiB fp16
  float* out0 = (float*)((char*)d_ws + U*2);
  float* out1 = out0 + O;
  float* part = out1 + O;                           // 8*O floats = 4 MiB

  k_compute_u  <<<dim3(II, 4),  dim3(256), 0, stream>>>(x, W, u);
  k_round0     <<<dim3(BB*NN),  dim3(256), 0, stream>>>(u, out0);
  k_round_reg  <<<dim3(8, BB),  dim3(256), 0, stream>>>(u, out0, part);
  k_reduce_part<<<dim3(512),    dim3(256), 0, stream>>>(part, out1);
  k_round_reg  <<<dim3(8, BB),  dim3(256), 0, stream>>>(u, out1, part);
  k_reduce_len <<<dim3(BB*NN),  dim3(64),  0, stream>>>(part, dout);
}